// Round 6
// baseline (477.485 us; speedup 1.0000x reference)
//
#include <hip/hip_runtime.h>
#include <cstdint>

typedef unsigned short u16;
typedef __attribute__((ext_vector_type(8))) short short8;
typedef __attribute__((ext_vector_type(8))) unsigned short ushort8;
typedef __attribute__((ext_vector_type(4))) float floatx4;
typedef __attribute__((ext_vector_type(8))) _Float16 half8;

#define S_LEN 1024
#define BATCH 64
#define EDIM 1024
#define UDIM 1024
#define VOCAB 32000
#define NTOT (3 * UDIM)        // 3072
#define CT 64                  // timesteps per scan chunk
#define NC (S_LEN / CT)        // 16 chunks
// LDS geometry (u16 elements): A = 2 halves x 4096, B = 2 halves x 6144
#define A_HALF 4096
#define B_BASE 8192
#define B_HALF 6144

__device__ __forceinline__ u16 f2bf(float x) {
  unsigned u = __float_as_uint(x);
  return (u16)((u + 0x7fffu + ((u >> 16) & 1u)) >> 16);  // RNE, inputs are finite
}

// async global->LDS, 16B per lane. HW writes LDS LINEARLY: wave-uniform base
// + lane*16 (m104/m108). All swizzling must live in the GLOBAL address.
__device__ __forceinline__ void async16(const u16* g, u16* s) {
  __builtin_amdgcn_global_load_lds(
      (__attribute__((address_space(1))) void*)(uintptr_t)g,
      (__attribute__((address_space(3))) void*)(uintptr_t)s,
      16, 0, 0);
}

__device__ __forceinline__ float sigm(float x) {
  return __builtin_amdgcn_rcpf(1.f + __expf(-x));
}

// ------- convert emb fp32 -> bf16 (grid-stride, dual-ILP stream) -------
__global__ __launch_bounds__(256) void conv_emb(const float4* __restrict__ in,
                                                ushort4* __restrict__ out, int n4) {
  const int stride = gridDim.x * 256;
  int i = blockIdx.x * 256 + threadIdx.x;
  for (; i + stride < n4; i += 2 * stride) {
    float4 v0 = in[i];
    float4 v1 = in[i + stride];
    ushort4 o0, o1;
    o0.x = f2bf(v0.x); o0.y = f2bf(v0.y); o0.z = f2bf(v0.z); o0.w = f2bf(v0.w);
    o1.x = f2bf(v1.x); o1.y = f2bf(v1.y); o1.z = f2bf(v1.z); o1.w = f2bf(v1.w);
    out[i] = o0;
    out[i + stride] = o1;
  }
  if (i < n4) {
    float4 v = in[i];
    ushort4 o;
    o.x = f2bf(v.x); o.y = f2bf(v.y); o.z = f2bf(v.z); o.w = f2bf(v.w);
    out[i] = o;
  }
}

// ------- transpose+convert W[E,U] fp32 -> Wt[U,E] bf16, 3 mats concat -------
__global__ __launch_bounds__(256) void conv_wt(const float* __restrict__ Wf,
                                               const float* __restrict__ Wi,
                                               const float* __restrict__ Wh,
                                               u16* __restrict__ wtB) {
  __shared__ float t[32][33];
  const float* W = (blockIdx.z == 0) ? Wf : ((blockIdx.z == 1) ? Wi : Wh);
  int bx = blockIdx.x * 32;  // n (input col)
  int by = blockIdx.y * 32;  // k (input row)
  int tx = threadIdx.x, ty = threadIdx.y;
  for (int j = 0; j < 32; j += 8)
    t[ty + j][tx] = W[(size_t)(by + ty + j) * UDIM + bx + tx];
  __syncthreads();
  u16* out = wtB + (size_t)blockIdx.z * UDIM * EDIM;
  for (int j = 0; j < 32; j += 8)
    out[(size_t)(bx + ty + j) * EDIM + by + tx] = f2bf(t[tx][ty + j]);
}

// ---- per-VOCAB-row gate table: 3-gate GEMM + gate nonlinearity epilogue ----
// M = 32000 = 250 m-tiles of 128 emb rows; n-tile = 64 u-cols x 3 gates.
// Half-K (BK=32) pipeline in R1's 40KB footprint. Each half is a physically
// contiguous LDS region (write side LINEAR: dest = halfbase + idx*16B, as
// global_load_lds requires); the conflict-breaking permutation lives in the
// GLOBAL source: slot (r,pos) holds sub-chunk pos ^ ((r>>1)&3). Read side:
// lane (fq,fr) reads pos fq^((fr>>1)&3) -> content sub=fq; bank-quad =
// 4*(fr&1) + that pos -> each quad 2x per 16-lane group (free, m136).
// Phase p: wait vmcnt(5) (drains S(p), keeps S(p+1) flying) -> barrier ->
// 24 MFMA (setprio 1) -> barrier -> issue S(p+2). Stage has a full compute
// phase + 2 barriers to land vs R1's issue-then-drain. 40KB -> 3 blocks/CU.
__global__ __launch_bounds__(256, 3) void gate_gemm(
    const u16* __restrict__ embB, const u16* __restrict__ wtB,
    const float* __restrict__ bfp, const float* __restrict__ bip,
    const float* __restrict__ bhp, u16* __restrict__ FG) {
  __shared__ __align__(16) u16 SM[2 * A_HALF + 2 * B_HALF];  // 40 KB

  const int tid = threadIdx.x;
  const int wave = tid >> 6;
  const int lane = tid & 63;

  // XCD map (bijective over 4000 blocks): XCD x owns utiles {2x, 2x+1};
  // consecutive slots on an XCD share the mtile -> A fetched once into that
  // XCD's L2, twin block hits; the XCD's 2 B-slices stay L2-resident.
  const int g = blockIdx.x;
  const int x = g & 7;
  const int s = g >> 3;              // 0..499
  const int mtile = s >> 1;          // 0..249
  const int utile = x * 2 + (s & 1); // 0..15
  const int m0 = mtile * 128;
  const int u0 = utile * 64;

  // staging maps: LDS dest is linear idx*16B within the half; global source
  // carries the swizzle sub = (idx&3) ^ ((r>>1)&3).
  const u16* gA[2]; int loA[2];
  const u16* gB[3]; int loB[3];
#pragma unroll
  for (int j = 0; j < 2; ++j) {
    int idx = j * 256 + tid;       // 0..511
    int r = idx >> 2;              // 0..127
    int sub = (idx & 3) ^ ((r >> 1) & 3);
    gA[j] = embB + (size_t)(m0 + r) * EDIM + sub * 8;
    loA[j] = idx * 8;
  }
#pragma unroll
  for (int j = 0; j < 3; ++j) {
    int idx = j * 256 + tid;       // 0..767
    int r = idx >> 2;              // 0..191
    int gr = (r >> 6) * UDIM + u0 + (r & 63);    // gate*1024 + u
    int sub = (idx & 3) ^ ((r >> 1) & 3);
    gB[j] = wtB + (size_t)gr * EDIM + sub * 8;
    loB[j] = idx * 8;
  }

  floatx4 acc[8][3] = {};
  const int fr = lane & 15;
  const int fq = lane >> 4;
  const int un = wave * 16 + fr;  // u-col within block's 64
  const int crd = (fq ^ ((fr >> 1) & 3)) * 8;  // read pos (u16 elems)

// phase p covers global K [p*32, p*32+32); h = p&1 selects the LDS half
#define STAGE(p, h)                                                  \
  do {                                                               \
    const int kb_ = (p) * 32;                                        \
    _Pragma("unroll") for (int j = 0; j < 2; ++j)                    \
        async16(gA[j] + kb_, &SM[(h) * A_HALF + loA[j]]);            \
    _Pragma("unroll") for (int j = 0; j < 3; ++j)                    \
        async16(gB[j] + kb_, &SM[B_BASE + (h) * B_HALF + loB[j]]);   \
  } while (0)

#define COMPUTE(h)                                                   \
  do {                                                               \
    const u16* Ah = SM + (h) * A_HALF;                               \
    const u16* Bh = SM + B_BASE + (h) * B_HALF;                      \
    short8 b0 = *(const short8*)&Bh[(0 * 64 + un) * 32 + crd];       \
    short8 b1 = *(const short8*)&Bh[(1 * 64 + un) * 32 + crd];       \
    short8 b2 = *(const short8*)&Bh[(2 * 64 + un) * 32 + crd];       \
    __builtin_amdgcn_s_setprio(1);                                   \
    _Pragma("unroll") for (int mt = 0; mt < 8; ++mt) {               \
      short8 am = *(const short8*)&Ah[(mt * 16 + fr) * 32 + crd];    \
      acc[mt][0] = __builtin_amdgcn_mfma_f32_16x16x32_bf16(am, b0, acc[mt][0], 0, 0, 0); \
      acc[mt][1] = __builtin_amdgcn_mfma_f32_16x16x32_bf16(am, b1, acc[mt][1], 0, 0, 0); \
      acc[mt][2] = __builtin_amdgcn_mfma_f32_16x16x32_bf16(am, b2, acc[mt][2], 0, 0, 0); \
    }                                                                \
    __builtin_amdgcn_s_setprio(0);                                   \
  } while (0)

  // prologue: issue S(0), S(1) (10 loads in flight)
  STAGE(0, 0);
  STAGE(1, 1);
  __builtin_amdgcn_sched_barrier(0);

  for (int t = 0; t < 15; ++t) {
    // phase 2t (h=0): drain S(2t); S(2t+1)'s 5 loads stay in flight
    asm volatile("s_waitcnt vmcnt(5)" ::: "memory");
    __builtin_amdgcn_s_barrier();
    __builtin_amdgcn_sched_barrier(0);
    COMPUTE(0);
    __builtin_amdgcn_sched_barrier(0);
    __builtin_amdgcn_s_barrier();
    STAGE(2 * t + 2, 0);
    __builtin_amdgcn_sched_barrier(0);
    // phase 2t+1 (h=1)
    asm volatile("s_waitcnt vmcnt(5)" ::: "memory");
    __builtin_amdgcn_s_barrier();
    __builtin_amdgcn_sched_barrier(0);
    COMPUTE(1);
    __builtin_amdgcn_sched_barrier(0);
    __builtin_amdgcn_s_barrier();
    STAGE(2 * t + 3, 1);
    __builtin_amdgcn_sched_barrier(0);
  }
  // phase 30 (no further stages)
  asm volatile("s_waitcnt vmcnt(5)" ::: "memory");
  __builtin_amdgcn_s_barrier();
  __builtin_amdgcn_sched_barrier(0);
  COMPUTE(0);
  __builtin_amdgcn_sched_barrier(0);
  __builtin_amdgcn_s_barrier();
  // phase 31
  asm volatile("s_waitcnt vmcnt(0)" ::: "memory");
  __builtin_amdgcn_s_barrier();
  __builtin_amdgcn_sched_barrier(0);
  COMPUTE(1);
  __syncthreads();  // all reads done before epilogue overlays SM
#undef STAGE
#undef COMPUTE

  // ---- epilogue: gate nonlinearity -> interleaved (F,G) f16 pairs ----
  // C/D layout: col=lane&15 (u), row=(lane>>4)*4+reg. row = mt*16+fq*4+r.
  // LDS restage overlays SM (dead now). Pair-u32 write at un ^ ((fq&1)<<4)
  // spreads a wave's stores over all 32 banks (2-way, free).
  const int ug = u0 + un;
  const float bfv = bfp[ug], biv = bip[ug], bhv = bhp[ug];
  u16* FGs = SM;  // 128 rows x 64 pairs x u32 = 32 KB
  const int up = un ^ ((fq & 1) << 4);
#pragma unroll
  for (int mt = 0; mt < 8; ++mt) {
#pragma unroll
    for (int r = 0; r < 4; ++r) {
      float fs = sigm(acc[mt][0][r] + bfv);
      float is = sigm(acc[mt][1][r] + biv);
      float hv = acc[mt][2][r] + bhv;
      float inv = __builtin_amdgcn_rcpf(fs + is);
      float fn = fs * inv;
      float gv = is * inv * hv;
      int row = mt * 16 + fq * 4 + r;
      unsigned pkfg = (unsigned)__builtin_bit_cast(u16, (_Float16)fn) |
                      ((unsigned)__builtin_bit_cast(u16, (_Float16)gv) << 16);
      *(unsigned*)&FGs[row * 128 + up * 2] = pkfg;
    }
  }
  __syncthreads();
  // 128 rows x 16 chunks of 16B; un-group cc was written at cc ^ (fqpar<<2)
#pragma unroll
  for (int j = 0; j < 8; ++j) {
    int idx = j * 256 + tid;
    int row = idx >> 4, cc = idx & 15;
    int ccp = cc ^ (((row >> 2) & 1) << 2);
    *(ushort8*)&FG[(size_t)(m0 + row) * (2 * UDIM) + u0 * 2 + cc * 8] =
        *(const ushort8*)&FGs[row * 128 + ccp * 8];
  }
}

// ---- gather precomputed (fn, g) pairs per token + 64-step chunk scan ----
// block = (b, chunk c): 256 threads x 4 u-cols, serial over 64 timesteps.
// One 16B load per (t, thread) from the interleaved table; 8 FMA compute.
__global__ __launch_bounds__(256) void scan_gather(
    const int* __restrict__ sent, const u16* __restrict__ FG,
    float* __restrict__ Fc, float* __restrict__ Gc) {
  const int b = blockIdx.x >> 4;
  const int c = blockIdx.x & (NC - 1);
  const int tid = threadIdx.x;
  __shared__ int toks[CT];
  if (tid < CT) toks[tid] = sent[b * S_LEN + c * CT + tid];
  __syncthreads();
  const int uo2 = tid * 8;  // u16 offset within a 2048-u16 row
  floatx4 F = {1.f, 1.f, 1.f, 1.f};
  floatx4 G = {0.f, 0.f, 0.f, 0.f};
#pragma unroll 8
  for (int t = 0; t < CT; ++t) {
    const size_t ro = (size_t)toks[t] * (2 * UDIM) + uo2;
    half8 fg = __builtin_bit_cast(half8, *(const ushort8*)&FG[ro]);
    floatx4 fn = {(float)fg[0], (float)fg[2], (float)fg[4], (float)fg[6]};
    floatx4 gv = {(float)fg[1], (float)fg[3], (float)fg[5], (float)fg[7]};
    G = fn * G + gv;   // h' = fn*h + g composed left-to-right
    F = F * fn;
  }
  const size_t o = (size_t)c * (BATCH * UDIM) + (size_t)b * UDIM + tid * 4;
  *(floatx4*)&Fc[o] = F;
  *(floatx4*)&Gc[o] = G;
}

// ---------------- combine chunks + MLP head ----------------
__global__ __launch_bounds__(256) void mlp_head(
    const float* __restrict__ Fc, const float* __restrict__ Gc,
    const float* __restrict__ W1, const float* __restrict__ b1,
    const float* __restrict__ W2, const float* __restrict__ b2,
    float* __restrict__ out) {
  const int b = blockIdx.x;
  const int tid = threadIdx.x;
  __shared__ float h_s[UDIM];
  __shared__ float z1[64];
  for (int u = tid; u < UDIM; u += 256) {
    float h = 0.f;
#pragma unroll
    for (int c = 0; c < NC; ++c) {
      float F = Fc[c * (BATCH * UDIM) + b * UDIM + u];
      float G = Gc[c * (BATCH * UDIM) + b * UDIM + u];
      h = F * h + G;
    }
    h_s[u] = h;
  }
  __syncthreads();
  const int j = tid >> 2, p = tid & 3;
  float partial = 0.f;
  for (int u = p * 256; u < p * 256 + 256; ++u) partial += h_s[u] * W1[u * 64 + j];
  partial += __shfl_down(partial, 1);
  partial += __shfl_down(partial, 2);
  if (p == 0) z1[j] = partial + b1[j];
  __syncthreads();
  if (tid < 64) {
    float v = z1[tid] * W2[tid];
#pragma unroll
    for (int off = 32; off > 0; off >>= 1) v += __shfl_down(v, off);
    if (tid == 0) out[b] = 1.f / (1.f + __expf(-(v + b2[0])));
  }
}

extern "C" void kernel_launch(void* const* d_in, const int* in_sizes, int n_in,
                              void* d_out, int out_size, void* d_ws, size_t ws_size,
                              hipStream_t stream) {
  const int* sent = (const int*)d_in[0];
  const float* emb = (const float*)d_in[1];
  const float* Wf = (const float*)d_in[2];
  const float* bf_ = (const float*)d_in[3];
  const float* Wi = (const float*)d_in[4];
  const float* bi_ = (const float*)d_in[5];
  const float* Wh = (const float*)d_in[6];
  const float* bh_ = (const float*)d_in[7];
  const float* W1 = (const float*)d_in[8];
  const float* b1 = (const float*)d_in[9];
  const float* W2 = (const float*)d_in[10];
  const float* b2 = (const float*)d_in[11];
  float* out = (float*)d_out;

  // workspace layout (~207 MiB)
  char* ws = (char*)d_ws;
  u16* embB = (u16*)ws;   ws += (size_t)VOCAB * EDIM * 2;         //  65,536,000
  u16* wtB = (u16*)ws;    ws += (size_t)NTOT * EDIM * 2;          //   6,291,456
  u16* FG = (u16*)ws;     ws += (size_t)VOCAB * UDIM * 2 * 2;     // 131,072,000
  float* Fc = (float*)ws; ws += (size_t)NC * BATCH * UDIM * 4;    //   4,194,304
  float* Gc = (float*)ws; ws += (size_t)NC * BATCH * UDIM * 4;    //   4,194,304

  int n4 = (int)((size_t)VOCAB * EDIM / 4);
  hipLaunchKernelGGL(conv_emb, dim3(2048), dim3(256), 0, stream,
                     (const float4*)emb, (ushort4*)embB, n4);
  hipLaunchKernelGGL(conv_wt, dim3(32, 32, 3), dim3(32, 8), 0, stream, Wf, Wi, Wh, wtB);
  hipLaunchKernelGGL(gate_gemm, dim3((VOCAB / 128) * (NTOT / 192)), dim3(256), 0, stream,
                     embB, wtB, bf_, bi_, bh_, FG);
  hipLaunchKernelGGL(scan_gather, dim3(BATCH * NC), dim3(256), 0, stream,
                     sent, FG, Fc, Gc);
  hipLaunchKernelGGL(mlp_head, dim3(BATCH), dim3(256), 0, stream, Fc, Gc, W1, b1, W2, b2, out);
}

// Round 7
// 470.250 us; speedup vs baseline: 1.0154x; 1.0154x over previous
//
#include <hip/hip_runtime.h>
#include <cstdint>

typedef unsigned short u16;
typedef __attribute__((ext_vector_type(8))) short short8;
typedef __attribute__((ext_vector_type(8))) unsigned short ushort8;
typedef __attribute__((ext_vector_type(4))) float floatx4;
typedef __attribute__((ext_vector_type(8))) _Float16 half8;

#define S_LEN 1024
#define BATCH 64
#define EDIM 1024
#define UDIM 1024
#define VOCAB 32000
#define NTOT (3 * UDIM)        // 3072
#define CT 64                  // timesteps per scan chunk
#define NC (S_LEN / CT)        // 16 chunks
#define NWT 3072               // conv_wt tiles (32x32x3)
#define NCE 2048               // conv_emb grid-stride blocks

__device__ __forceinline__ u16 f2bf(float x) {
  unsigned u = __float_as_uint(x);
  return (u16)((u + 0x7fffu + ((u >> 16) & 1u)) >> 16);  // RNE, inputs are finite
}

// async global->LDS, 16B per lane. HW writes LDS LINEARLY: wave-uniform base
// + lane*16 (m104/m108). All swizzling must live in the GLOBAL address.
__device__ __forceinline__ void async16(const u16* g, u16* s) {
  __builtin_amdgcn_global_load_lds(
      (__attribute__((address_space(1))) void*)(uintptr_t)g,
      (__attribute__((address_space(3))) void*)(uintptr_t)s,
      16, 0, 0);
}

__device__ __forceinline__ float sigm(float x) {
  return __builtin_amdgcn_rcpf(1.f + __expf(-x));
}

// ---- fused preprocessing: one launch for both weight transpose + emb cast ----
// blocks [0, NWT): transpose+convert W[E,U] fp32 -> Wt[U,E] bf16 (3 mats);
// blocks [NWT, NWT+NCE): grid-stride dual-ILP emb fp32 -> bf16 stream.
// Branch is on blockIdx -> wave-uniform, __syncthreads stays block-uniform.
__global__ __launch_bounds__(256) void conv_pre(
    const float* __restrict__ Wf, const float* __restrict__ Wi,
    const float* __restrict__ Wh, u16* __restrict__ wtB,
    const float4* __restrict__ embIn, ushort4* __restrict__ embOut, int n4) {
  const int b = blockIdx.x;
  const int tid = threadIdx.x;
  if (b < NWT) {
    __shared__ float t[32][33];
    const int z = b >> 10;            // 0..2  matrix
    const int rem = b & 1023;
    const int by = (rem >> 5) * 32;   // k (input row)
    const int bx = (rem & 31) * 32;   // n (input col)
    const float* W = (z == 0) ? Wf : ((z == 1) ? Wi : Wh);
    const int tx = tid & 31, ty = tid >> 5;  // ty 0..7
    for (int j = 0; j < 32; j += 8)
      t[ty + j][tx] = W[(size_t)(by + ty + j) * UDIM + bx + tx];
    __syncthreads();
    u16* out = wtB + (size_t)z * UDIM * EDIM;
    for (int j = 0; j < 32; j += 8)
      out[(size_t)(bx + ty + j) * EDIM + by + tx] = f2bf(t[tx][ty + j]);
  } else {
    const int stride = NCE * 256;
    int i = (b - NWT) * 256 + tid;
    for (; i + stride < n4; i += 2 * stride) {
      float4 v0 = embIn[i];
      float4 v1 = embIn[i + stride];
      ushort4 o0, o1;
      o0.x = f2bf(v0.x); o0.y = f2bf(v0.y); o0.z = f2bf(v0.z); o0.w = f2bf(v0.w);
      o1.x = f2bf(v1.x); o1.y = f2bf(v1.y); o1.z = f2bf(v1.z); o1.w = f2bf(v1.w);
      embOut[i] = o0;
      embOut[i + stride] = o1;
    }
    if (i < n4) {
      float4 v = embIn[i];
      ushort4 o;
      o.x = f2bf(v.x); o.y = f2bf(v.y); o.z = f2bf(v.z); o.w = f2bf(v.w);
      embOut[i] = o;
    }
  }
}

// ---- per-VOCAB-row gate table: 3-gate GEMM + gate nonlinearity epilogue ----
// M = 32000 = 250 m-tiles of 128 emb rows; n-tile = 64 u-cols x 3 gates.
// K-loop is the R1-measured optimum (194us, 48% MfmaUtil): 10x async16 ->
// __syncthreads -> 48 MFMA -> __syncthreads. Schedule experiments R3/R4/R6
// (reg-pipeline / 80KB dbuf / half-K counted-vmcnt) all regressed (362/211/
// 220us) -- implicit wave overlap at 3 blocks/CU already captures the gain
// (guide m99-m141). Epilogue: conflict-free interleaved (F,G) f16 pairs.
__global__ __launch_bounds__(256, 3) void gate_gemm(
    const u16* __restrict__ embB, const u16* __restrict__ wtB,
    const float* __restrict__ bfp, const float* __restrict__ bip,
    const float* __restrict__ bhp, u16* __restrict__ FG) {
  __shared__ __align__(16) u16 SM[128 * 64 + 192 * 64];  // 40 KB (As | Bs)
  u16* As = SM;
  u16* Bs = SM + 128 * 64;

  const int tid = threadIdx.x;
  const int wave = tid >> 6;
  const int lane = tid & 63;

  // XCD map (bijective over 4000 blocks): XCD x owns utiles {2x, 2x+1};
  // consecutive slots on an XCD share the mtile -> A fetched once into that
  // XCD's L2, twin block hits; the XCD's 2 B-slices stay L2-resident.
  const int g = blockIdx.x;
  const int x = g & 7;
  const int s = g >> 3;              // 0..499
  const int mtile = s >> 1;          // 0..249
  const int utile = x * 2 + (s & 1); // 0..15
  const int m0 = mtile * 128;
  const int u0 = utile * 64;

  // staging maps, XOR-swizzled at 16B-chunk granularity in the GLOBAL source:
  // LDS slot (row r, chunk c) holds global chunk c^(r&7) -> conflict-free
  // ds_read_b128 on the read side. LDS dest stays linear (idx*16B).
  const u16* gA[4]; int loA[4];
  const u16* gB[6]; int loB[6];
#pragma unroll
  for (int j = 0; j < 4; ++j) {
    int idx = j * 256 + tid;
    int r = idx >> 3;
    int cg = (idx & 7) ^ (r & 7);
    gA[j] = embB + (size_t)(m0 + r) * EDIM + cg * 8;
    loA[j] = idx * 8;
  }
#pragma unroll
  for (int j = 0; j < 6; ++j) {
    int idx = j * 256 + tid;
    int r = idx >> 3;                            // 0..191
    int gr = (r >> 6) * UDIM + u0 + (r & 63);    // gate*1024 + u
    int cg = (idx & 7) ^ (r & 7);
    gB[j] = wtB + (size_t)gr * EDIM + cg * 8;
    loB[j] = idx * 8;
  }

  floatx4 acc[8][3] = {};
  const int fr = lane & 15;
  const int fq = lane >> 4;
  const int fr7 = fr & 7;
  const int un = wave * 16 + fr;  // u-col within block's 64

  for (int k0 = 0; k0 < EDIM; k0 += 64) {
#pragma unroll
    for (int j = 0; j < 4; ++j) async16(gA[j] + k0, &As[loA[j]]);
#pragma unroll
    for (int j = 0; j < 6; ++j) async16(gB[j] + k0, &Bs[loB[j]]);
    __syncthreads();
#pragma unroll
    for (int kk = 0; kk < 2; ++kk) {
      const int swz = ((kk * 4 + fq) ^ fr7) * 8;
      short8 b0 = *(const short8*)&Bs[(0 * 64 + un) * 64 + swz];
      short8 b1 = *(const short8*)&Bs[(1 * 64 + un) * 64 + swz];
      short8 b2 = *(const short8*)&Bs[(2 * 64 + un) * 64 + swz];
#pragma unroll
      for (int mt = 0; mt < 8; ++mt) {
        short8 am = *(const short8*)&As[(mt * 16 + fr) * 64 + swz];
        acc[mt][0] = __builtin_amdgcn_mfma_f32_16x16x32_bf16(am, b0, acc[mt][0], 0, 0, 0);
        acc[mt][1] = __builtin_amdgcn_mfma_f32_16x16x32_bf16(am, b1, acc[mt][1], 0, 0, 0);
        acc[mt][2] = __builtin_amdgcn_mfma_f32_16x16x32_bf16(am, b2, acc[mt][2], 0, 0, 0);
      }
    }
    __syncthreads();
  }

  // ---- epilogue: gate nonlinearity -> interleaved (F,G) f16 pairs ----
  // C/D layout: col=lane&15 (u), row=(lane>>4)*4+reg. row = mt*16+fq*4+r.
  // LDS restage overlays SM (dead now). Pair-u32 write at un ^ ((fq&1)<<4)
  // spreads a wave's stores over all 32 banks (2-way, free; conflicts=0 R4/R6).
  const int ug = u0 + un;
  const float bfv = bfp[ug], biv = bip[ug], bhv = bhp[ug];
  u16* FGs = SM;  // 128 rows x 64 pairs x u32 = 32 KB
  const int up = un ^ ((fq & 1) << 4);
#pragma unroll
  for (int mt = 0; mt < 8; ++mt) {
#pragma unroll
    for (int r = 0; r < 4; ++r) {
      float fs = sigm(acc[mt][0][r] + bfv);
      float is = sigm(acc[mt][1][r] + biv);
      float hv = acc[mt][2][r] + bhv;
      float inv = __builtin_amdgcn_rcpf(fs + is);
      float fn = fs * inv;
      float gv = is * inv * hv;
      int row = mt * 16 + fq * 4 + r;
      unsigned pkfg = (unsigned)__builtin_bit_cast(u16, (_Float16)fn) |
                      ((unsigned)__builtin_bit_cast(u16, (_Float16)gv) << 16);
      *(unsigned*)&FGs[row * 128 + up * 2] = pkfg;
    }
  }
  __syncthreads();
  // 128 rows x 16 chunks of 16B; un-group cc was written at cc ^ (fqpar<<2)
#pragma unroll
  for (int j = 0; j < 8; ++j) {
    int idx = j * 256 + tid;
    int row = idx >> 4, cc = idx & 15;
    int ccp = cc ^ (((row >> 2) & 1) << 2);
    *(ushort8*)&FG[(size_t)(m0 + row) * (2 * UDIM) + u0 * 2 + cc * 8] =
        *(const ushort8*)&FGs[row * 128 + ccp * 8];
  }
}

// ---- gather precomputed (fn, g) pairs per token + 64-step chunk scan ----
// block = (b, chunk c): 256 threads x 4 u-cols, serial over 64 timesteps.
// One 16B load per (t, thread); block reads each token row as one contiguous
// 4KB line. ~268 MB total at ~5.9 TB/s effective -- near BW ceiling.
__global__ __launch_bounds__(256) void scan_gather(
    const int* __restrict__ sent, const u16* __restrict__ FG,
    float* __restrict__ Fc, float* __restrict__ Gc) {
  const int b = blockIdx.x >> 4;
  const int c = blockIdx.x & (NC - 1);
  const int tid = threadIdx.x;
  __shared__ int toks[CT];
  if (tid < CT) toks[tid] = sent[b * S_LEN + c * CT + tid];
  __syncthreads();
  const int uo2 = tid * 8;  // u16 offset within a 2048-u16 row
  floatx4 F = {1.f, 1.f, 1.f, 1.f};
  floatx4 G = {0.f, 0.f, 0.f, 0.f};
#pragma unroll 8
  for (int t = 0; t < CT; ++t) {
    const size_t ro = (size_t)toks[t] * (2 * UDIM) + uo2;
    half8 fg = __builtin_bit_cast(half8, *(const ushort8*)&FG[ro]);
    floatx4 fn = {(float)fg[0], (float)fg[2], (float)fg[4], (float)fg[6]};
    floatx4 gv = {(float)fg[1], (float)fg[3], (float)fg[5], (float)fg[7]};
    G = fn * G + gv;   // h' = fn*h + g composed left-to-right
    F = F * fn;
  }
  const size_t o = (size_t)c * (BATCH * UDIM) + (size_t)b * UDIM + tid * 4;
  *(floatx4*)&Fc[o] = F;
  *(floatx4*)&Gc[o] = G;
}

// ---------------- combine chunks + MLP head ----------------
__global__ __launch_bounds__(256) void mlp_head(
    const float* __restrict__ Fc, const float* __restrict__ Gc,
    const float* __restrict__ W1, const float* __restrict__ b1,
    const float* __restrict__ W2, const float* __restrict__ b2,
    float* __restrict__ out) {
  const int b = blockIdx.x;
  const int tid = threadIdx.x;
  __shared__ float h_s[UDIM];
  __shared__ float z1[64];
  for (int u = tid; u < UDIM; u += 256) {
    float h = 0.f;
#pragma unroll
    for (int c = 0; c < NC; ++c) {
      float F = Fc[c * (BATCH * UDIM) + b * UDIM + u];
      float G = Gc[c * (BATCH * UDIM) + b * UDIM + u];
      h = F * h + G;
    }
    h_s[u] = h;
  }
  __syncthreads();
  const int j = tid >> 2, p = tid & 3;
  float partial = 0.f;
  for (int u = p * 256; u < p * 256 + 256; ++u) partial += h_s[u] * W1[u * 64 + j];
  partial += __shfl_down(partial, 1);
  partial += __shfl_down(partial, 2);
  if (p == 0) z1[j] = partial + b1[j];
  __syncthreads();
  if (tid < 64) {
    float v = z1[tid] * W2[tid];
#pragma unroll
    for (int off = 32; off > 0; off >>= 1) v += __shfl_down(v, off);
    if (tid == 0) out[b] = 1.f / (1.f + __expf(-(v + b2[0])));
  }
}

extern "C" void kernel_launch(void* const* d_in, const int* in_sizes, int n_in,
                              void* d_out, int out_size, void* d_ws, size_t ws_size,
                              hipStream_t stream) {
  const int* sent = (const int*)d_in[0];
  const float* emb = (const float*)d_in[1];
  const float* Wf = (const float*)d_in[2];
  const float* bf_ = (const float*)d_in[3];
  const float* Wi = (const float*)d_in[4];
  const float* bi_ = (const float*)d_in[5];
  const float* Wh = (const float*)d_in[6];
  const float* bh_ = (const float*)d_in[7];
  const float* W1 = (const float*)d_in[8];
  const float* b1 = (const float*)d_in[9];
  const float* W2 = (const float*)d_in[10];
  const float* b2 = (const float*)d_in[11];
  float* out = (float*)d_out;

  // workspace layout (~207 MiB)
  char* ws = (char*)d_ws;
  u16* embB = (u16*)ws;   ws += (size_t)VOCAB * EDIM * 2;         //  65,536,000
  u16* wtB = (u16*)ws;    ws += (size_t)NTOT * EDIM * 2;          //   6,291,456
  u16* FG = (u16*)ws;     ws += (size_t)VOCAB * UDIM * 2 * 2;     // 131,072,000
  float* Fc = (float*)ws; ws += (size_t)NC * BATCH * UDIM * 4;    //   4,194,304
  float* Gc = (float*)ws; ws += (size_t)NC * BATCH * UDIM * 4;    //   4,194,304

  int n4 = (int)((size_t)VOCAB * EDIM / 4);
  hipLaunchKernelGGL(conv_pre, dim3(NWT + NCE), dim3(256), 0, stream,
                     Wf, Wi, Wh, wtB, (const float4*)emb, (ushort4*)embB, n4);
  hipLaunchKernelGGL(gate_gemm, dim3((VOCAB / 128) * (NTOT / 192)), dim3(256), 0, stream,
                     embB, wtB, bf_, bi_, bh_, FG);
  hipLaunchKernelGGL(scan_gather, dim3(BATCH * NC), dim3(256), 0, stream,
                     sent, FG, Fc, Gc);
  hipLaunchKernelGGL(mlp_head, dim3(BATCH), dim3(256), 0, stream, Fc, Gc, W1, b1, W2, b2, out);
}